// Round 1
// baseline (153.045 us; speedup 1.0000x reference)
//
#include <hip/hip_runtime.h>

#define BATCH 8
#define NN 2048
#define FIN 128
#define FOUT 64
#define ROWS_TOTAL (BATCH * NN)           // 16384
#define ROWS_PER_WAVE 8
#define WAVES_PER_BLOCK 4
#define ROWS_PER_BLOCK (ROWS_PER_WAVE * WAVES_PER_BLOCK)  // 32

// ---------------------------------------------------------------------------
// K1: wh = h @ W  [rows][64],  wh1 = wh @ a[:64],  wh2 = wh @ a[64:]
// lane = output feature f; 8 rows per wave.
// ---------------------------------------------------------------------------
__global__ __launch_bounds__(256) void k1_proj(
        const float* __restrict__ h, const float* __restrict__ W,
        const float* __restrict__ a,
        float* __restrict__ wh, float* __restrict__ wh1, float* __restrict__ wh2) {
    const int tid  = threadIdx.x;
    const int lane = tid & 63;
    const int wid  = tid >> 6;
    const int gw   = blockIdx.x * WAVES_PER_BLOCK + wid;
    const int row0 = gw * ROWS_PER_WAVE;

    float acc[ROWS_PER_WAVE] = {0.f,0.f,0.f,0.f,0.f,0.f,0.f,0.f};
    const float* hrow = h + (size_t)row0 * FIN;

    #pragma unroll 2
    for (int kc = 0; kc < FIN / 4; ++kc) {
        // W column slice for this lane, 4 consecutive k
        float wv0 = W[(4*kc + 0) * FOUT + lane];
        float wv1 = W[(4*kc + 1) * FOUT + lane];
        float wv2 = W[(4*kc + 2) * FOUT + lane];
        float wv3 = W[(4*kc + 3) * FOUT + lane];
        #pragma unroll
        for (int r = 0; r < ROWS_PER_WAVE; ++r) {
            float4 h4 = *(const float4*)(hrow + r * FIN + 4*kc);
            acc[r] = fmaf(h4.x, wv0, acc[r]);
            acc[r] = fmaf(h4.y, wv1, acc[r]);
            acc[r] = fmaf(h4.z, wv2, acc[r]);
            acc[r] = fmaf(h4.w, wv3, acc[r]);
        }
    }

    const float a1 = a[lane];
    const float a2 = a[FOUT + lane];
    #pragma unroll
    for (int r = 0; r < ROWS_PER_WAVE; ++r) {
        const int row = row0 + r;
        wh[(size_t)row * FOUT + lane] = acc[r];
        float v1 = acc[r] * a1;
        float v2 = acc[r] * a2;
        #pragma unroll
        for (int m = 32; m >= 1; m >>= 1) {
            v1 += __shfl_xor(v1, m, 64);
            v2 += __shfl_xor(v2, m, 64);
        }
        if (lane == 0) { wh1[row] = v1; wh2[row] = v2; }
    }
}

// ---------------------------------------------------------------------------
// K2: fused masked-softmax + PV.  lane = feature f; 8 rows per wave.
// p_j = exp(leaky_relu(wh1[i]+wh2[j]) + adj[i][j])   (adj in {0,-1e9})
// out[i][f] = elu( (sum_j p_j * wh[j][f]) / (sum_j p_j) )
// ---------------------------------------------------------------------------
__global__ __launch_bounds__(256) void k2_attn(
        const float* __restrict__ adj, const float* __restrict__ wh,
        const float* __restrict__ wh1, const float* __restrict__ wh2,
        float* __restrict__ out) {
    const int tid  = threadIdx.x;
    const int lane = tid & 63;
    const int wid  = tid >> 6;
    const int gw   = blockIdx.x * WAVES_PER_BLOCK + wid;
    const int row0 = gw * ROWS_PER_WAVE;          // global row (b*N + i)
    const int b    = row0 / NN;                    // 8 rows never cross batch

    const float* whb  = wh  + (size_t)b * NN * FOUT;
    const float* wh2b = wh2 + (size_t)b * NN;

    float q[ROWS_PER_WAVE];
    #pragma unroll
    for (int r = 0; r < ROWS_PER_WAVE; ++r) q[r] = wh1[row0 + r];

    float acc[ROWS_PER_WAVE]  = {0.f,0.f,0.f,0.f,0.f,0.f,0.f,0.f};
    float lsum[ROWS_PER_WAVE] = {0.f,0.f,0.f,0.f,0.f,0.f,0.f,0.f};

    for (int jb = 0; jb < NN; jb += 64) {
        const float wh2v = wh2b[jb + lane];
        float p[ROWS_PER_WAVE];
        #pragma unroll
        for (int r = 0; r < ROWS_PER_WAVE; ++r) {
            float adjv = adj[(size_t)(row0 + r) * NN + jb + lane];
            float e  = q[r] + wh2v;
            float lr = fmaxf(e, 0.2f * e);      // leaky_relu, slope 0.2
            float s  = lr + adjv;               // mask fold: exp(-1e9+x) == 0
            float pv = __expf(s);
            p[r] = pv;
            lsum[r] += pv;
        }
        const float* whj = whb + (size_t)jb * FOUT + lane;
        #pragma unroll
        for (int jj = 0; jj < 64; ++jj) {
            float whv = whj[(size_t)jj * FOUT];
            #pragma unroll
            for (int r = 0; r < ROWS_PER_WAVE; ++r) {
                float pv = __uint_as_float(
                    __builtin_amdgcn_readlane(__float_as_uint(p[r]), jj));
                acc[r] = fmaf(pv, whv, acc[r]);
            }
        }
    }

    #pragma unroll
    for (int r = 0; r < ROWS_PER_WAVE; ++r) {
        float l = lsum[r];
        #pragma unroll
        for (int m = 32; m >= 1; m >>= 1) l += __shfl_xor(l, m, 64);
        float v = acc[r] / l;
        float res = (v > 0.f) ? v : (__expf(v) - 1.f);   // elu, alpha=1
        out[(size_t)(row0 + r) * FOUT + lane] = res;
    }
}

// ---------------------------------------------------------------------------
extern "C" void kernel_launch(void* const* d_in, const int* in_sizes, int n_in,
                              void* d_out, int out_size, void* d_ws, size_t ws_size,
                              hipStream_t stream) {
    const float* h   = (const float*)d_in[0];   // [8,2048,128]
    const float* adj = (const float*)d_in[1];   // [8,2048,2048]
    const float* W   = (const float*)d_in[2];   // [128,64]
    const float* a   = (const float*)d_in[3];   // [128,1]
    float* out = (float*)d_out;                 // [8,2048,64]

    float* wh  = (float*)d_ws;                      // 16384*64 floats
    float* wh1 = wh + (size_t)ROWS_TOTAL * FOUT;    // 16384
    float* wh2 = wh1 + ROWS_TOTAL;                  // 16384

    const int blocks = ROWS_TOTAL / ROWS_PER_BLOCK; // 512
    k1_proj<<<blocks, 256, 0, stream>>>(h, W, a, wh, wh1, wh2);
    k2_attn<<<blocks, 256, 0, stream>>>(adj, wh, wh1, wh2, out);
}

// Round 3
// 73.876 us; speedup vs baseline: 2.0716x; 2.0716x over previous
//
#include <hip/hip_runtime.h>
#include <hip/hip_bf16.h>

#define BATCH 8
#define NN 2048
#define FIN 128
#define FOUT 64
#define ROWS_TOTAL (BATCH * NN)           // 16384

typedef __attribute__((ext_vector_type(8))) short bf16x8;
typedef __attribute__((ext_vector_type(4))) float f32x4;
typedef __attribute__((ext_vector_type(8))) short short8;

__device__ inline short f2bf(float x) {
    __hip_bfloat16 b = __float2bfloat16(x);   // RNE
    short s;
    __builtin_memcpy(&s, &b, 2);
    return s;
}

// ---------------------------------------------------------------------------
// K1: wh = h @ W; store whT as bf16 [B][FOUT][NN]; wh1 = wh@a[:64], wh2 = wh@a[64:]
// lane = output feature f; 8 rows per wave; 4 waves/block => 32 rows/block.
// (validated in round 1 apart from the transposed bf16 store)
// ---------------------------------------------------------------------------
__global__ __launch_bounds__(256) void k1_proj(
        const float* __restrict__ h, const float* __restrict__ W,
        const float* __restrict__ a,
        short* __restrict__ whT, float* __restrict__ wh1, float* __restrict__ wh2) {
    const int tid  = threadIdx.x;
    const int lane = tid & 63;
    const int wid  = tid >> 6;
    const int gw   = blockIdx.x * 4 + wid;
    const int row0 = gw * 8;                 // global row
    const int b    = row0 >> 11;             // /NN
    const int rloc = row0 & (NN - 1);        // row within batch (multiple of 8)

    float acc[8] = {0.f,0.f,0.f,0.f,0.f,0.f,0.f,0.f};
    const float* hrow = h + (size_t)row0 * FIN;

    #pragma unroll 2
    for (int kc = 0; kc < FIN / 4; ++kc) {
        float wv0 = W[(4*kc + 0) * FOUT + lane];
        float wv1 = W[(4*kc + 1) * FOUT + lane];
        float wv2 = W[(4*kc + 2) * FOUT + lane];
        float wv3 = W[(4*kc + 3) * FOUT + lane];
        #pragma unroll
        for (int r = 0; r < 8; ++r) {
            float4 h4 = *(const float4*)(hrow + r * FIN + 4*kc);
            acc[r] = fmaf(h4.x, wv0, acc[r]);
            acc[r] = fmaf(h4.y, wv1, acc[r]);
            acc[r] = fmaf(h4.z, wv2, acc[r]);
            acc[r] = fmaf(h4.w, wv3, acc[r]);
        }
    }

    // whT[b][f=lane][rloc + r] as bf16, 8 consecutive -> one 16B store
    short8 st;
    #pragma unroll
    for (int r = 0; r < 8; ++r) st[r] = f2bf(acc[r]);
    *(short8*)(whT + ((size_t)b * FOUT + lane) * NN + rloc) = st;

    const float a1 = a[lane];
    const float a2 = a[FOUT + lane];
    #pragma unroll
    for (int r = 0; r < 8; ++r) {
        const int row = row0 + r;
        float v1 = acc[r] * a1;
        float v2 = acc[r] * a2;
        #pragma unroll
        for (int m = 32; m >= 1; m >>= 1) {
            v1 += __shfl_xor(v1, m, 64);
            v2 += __shfl_xor(v2, m, 64);
        }
        if (lane == 0) { wh1[row] = v1; wh2[row] = v2; }
    }
}

// ---------------------------------------------------------------------------
// K2: fused masked-softmax + PV via MFMA (16x16x32 bf16), layout-self-calibrated.
// Block = 16 rows; 4 waves partition j (tiles mod 4); partials combined in LDS.
// Markers measure the true (lane,reg)->(row,col) D-mapping at runtime:
//   rowM = mfma(idx,ones) -> 32*row;  colM = mfma(ones,idx) -> 32*col.
// Denominator l = mfma(P, ones) -> same layout as acc => consistent normalize.
// ---------------------------------------------------------------------------
__global__ __launch_bounds__(256) void k2_attn(
        const float* __restrict__ adj, const short* __restrict__ whT,
        const float* __restrict__ wh1, const float* __restrict__ wh2,
        float* __restrict__ out) {
    __shared__ float lds_acc[4][16][FOUT];
    __shared__ float lds_l[4][16];

    const int tid  = threadIdx.x;
    const int lane = tid & 63;
    const int w    = tid >> 6;
    const int row0 = blockIdx.x * 16;        // global row base
    const int b    = row0 >> 11;
    const int iloc = lane & 15;
    const int koff = (lane >> 4) * 8;

    const float* adjrow = adj + (size_t)(row0 + iloc) * NN;
    const float* wh2b   = wh2 + b * NN;
    const short* whTb   = whT + (size_t)b * FOUT * NN;
    const float  wh1v   = wh1[row0 + iloc];

    // --- layout self-calibration ---
    bf16x8 onesf, idxf;
    #pragma unroll
    for (int e = 0; e < 8; ++e) { onesf[e] = (short)0x3F80; idxf[e] = f2bf((float)iloc); }
    f32x4 rowM = {}, colM = {};
    rowM = __builtin_amdgcn_mfma_f32_16x16x32_bf16(idxf, onesf, rowM, 0, 0, 0);
    colM = __builtin_amdgcn_mfma_f32_16x16x32_bf16(onesf, idxf, colM, 0, 0, 0);
    int rmap[4], cmap[4];
    #pragma unroll
    for (int reg = 0; reg < 4; ++reg) {
        int r = (int)(rowM[reg] * 0.03125f + 0.5f);
        int c = (int)(colM[reg] * 0.03125f + 0.5f);
        rmap[reg] = min(max(r, 0), 15);
        cmap[reg] = min(max(c, 0), 15);
    }

    f32x4 acc[4] = {};
    f32x4 accl = {};

    #pragma unroll 2
    for (int k = 0; k < 16; ++k) {
        const int jt = ((k << 2) + w) << 5;   // (k*4 + w)*32
        const int j0 = jt + koff;

        float4 a0 = *(const float4*)(adjrow + j0);
        float4 a1 = *(const float4*)(adjrow + j0 + 4);
        float4 w0 = *(const float4*)(wh2b + j0);
        float4 w1 = *(const float4*)(wh2b + j0 + 4);

        float pv[8];
        {
            float e0 = wh1v + w0.x, e1 = wh1v + w0.y, e2 = wh1v + w0.z, e3 = wh1v + w0.w;
            float e4 = wh1v + w1.x, e5 = wh1v + w1.y, e6 = wh1v + w1.z, e7 = wh1v + w1.w;
            pv[0] = __expf(fmaxf(e0, 0.2f*e0) + a0.x);
            pv[1] = __expf(fmaxf(e1, 0.2f*e1) + a0.y);
            pv[2] = __expf(fmaxf(e2, 0.2f*e2) + a0.z);
            pv[3] = __expf(fmaxf(e3, 0.2f*e3) + a0.w);
            pv[4] = __expf(fmaxf(e4, 0.2f*e4) + a1.x);
            pv[5] = __expf(fmaxf(e5, 0.2f*e5) + a1.y);
            pv[6] = __expf(fmaxf(e6, 0.2f*e6) + a1.z);
            pv[7] = __expf(fmaxf(e7, 0.2f*e7) + a1.w);
        }
        bf16x8 afrag;
        #pragma unroll
        for (int e = 0; e < 8; ++e) afrag[e] = f2bf(pv[e]);

        accl = __builtin_amdgcn_mfma_f32_16x16x32_bf16(afrag, onesf, accl, 0, 0, 0);
        #pragma unroll
        for (int ft = 0; ft < 4; ++ft) {
            bf16x8 bfrag = *(const bf16x8*)(whTb + (size_t)(ft*16 + iloc) * NN + j0);
            acc[ft] = __builtin_amdgcn_mfma_f32_16x16x32_bf16(afrag, bfrag, acc[ft], 0, 0, 0);
        }
    }

    // stash partials in LDS using the MEASURED layout maps
    #pragma unroll
    for (int ft = 0; ft < 4; ++ft)
        #pragma unroll
        for (int reg = 0; reg < 4; ++reg)
            lds_acc[w][rmap[reg]][ft * 16 + cmap[reg]] = acc[ft][reg];
    #pragma unroll
    for (int reg = 0; reg < 4; ++reg)
        if (cmap[reg] == 0) lds_l[w][rmap[reg]] = accl[reg];
    __syncthreads();

    // combine across waves + normalize + elu; thread t -> f = t&63, 4 rows
    const int f  = tid & 63;
    const int r0 = tid >> 6;
    #pragma unroll
    for (int rr = 0; rr < 4; ++rr) {
        const int r = r0 * 4 + rr;
        float s = lds_acc[0][r][f] + lds_acc[1][r][f] + lds_acc[2][r][f] + lds_acc[3][r][f];
        float l = lds_l[0][r] + lds_l[1][r] + lds_l[2][r] + lds_l[3][r];
        float v = s / l;
        out[(size_t)(row0 + r) * FOUT + f] = (v > 0.f) ? v : (__expf(v) - 1.f);
    }
}

// ---------------------------------------------------------------------------
extern "C" void kernel_launch(void* const* d_in, const int* in_sizes, int n_in,
                              void* d_out, int out_size, void* d_ws, size_t ws_size,
                              hipStream_t stream) {
    const float* h   = (const float*)d_in[0];   // [8,2048,128]
    const float* adj = (const float*)d_in[1];   // [8,2048,2048]
    const float* W   = (const float*)d_in[2];   // [128,64]
    const float* a   = (const float*)d_in[3];   // [128,1]
    float* out = (float*)d_out;                 // [8,2048,64]

    short* whT = (short*)d_ws;                             // [8][64][2048] bf16 = 2 MB
    float* wh1 = (float*)(whT + (size_t)BATCH * FOUT * NN);// 16384 f32
    float* wh2 = wh1 + ROWS_TOTAL;                         // 16384 f32

    k1_proj<<<ROWS_TOTAL / 32, 256, 0, stream>>>(h, W, a, whT, wh1, wh2);
    k2_attn<<<ROWS_TOTAL / 16, 256, 0, stream>>>(adj, whT, wh1, wh2, out);
}

// Round 4
// 73.847 us; speedup vs baseline: 2.0725x; 1.0004x over previous
//
#include <hip/hip_runtime.h>
#include <hip/hip_bf16.h>

#define BATCH 8
#define NN 2048
#define FIN 128
#define FOUT 64
#define ROWS_TOTAL (BATCH * NN)           // 16384

typedef __attribute__((ext_vector_type(8))) short bf16x8;
typedef __attribute__((ext_vector_type(4))) float f32x4;
typedef __attribute__((ext_vector_type(8))) short short8;

__device__ inline short f2bf(float x) {
    __hip_bfloat16 b = __float2bfloat16(x);   // RNE
    short s;
    __builtin_memcpy(&s, &b, 2);
    return s;
}

// scores -> exp -> bf16 A-fragment for one 16x32 tile (8 j per lane)
__device__ inline bf16x8 score8(float q, float4 w0, float4 w1, float4 a0, float4 a1) {
    float p[8];
    float e;
    e = q + w0.x; p[0] = __expf(fmaxf(e, 0.2f * e) + a0.x);
    e = q + w0.y; p[1] = __expf(fmaxf(e, 0.2f * e) + a0.y);
    e = q + w0.z; p[2] = __expf(fmaxf(e, 0.2f * e) + a0.z);
    e = q + w0.w; p[3] = __expf(fmaxf(e, 0.2f * e) + a0.w);
    e = q + w1.x; p[4] = __expf(fmaxf(e, 0.2f * e) + a1.x);
    e = q + w1.y; p[5] = __expf(fmaxf(e, 0.2f * e) + a1.y);
    e = q + w1.z; p[6] = __expf(fmaxf(e, 0.2f * e) + a1.z);
    e = q + w1.w; p[7] = __expf(fmaxf(e, 0.2f * e) + a1.w);
    bf16x8 r;
    #pragma unroll
    for (int i = 0; i < 8; ++i) r[i] = f2bf(p[i]);
    return r;
}

// ---------------------------------------------------------------------------
// K1: wh = h @ W; store whT as bf16 [B][FOUT][NN]; wh1 = wh@a[:64], wh2 = wh@a[64:]
// (unchanged — validated)
// ---------------------------------------------------------------------------
__global__ __launch_bounds__(256) void k1_proj(
        const float* __restrict__ h, const float* __restrict__ W,
        const float* __restrict__ a,
        short* __restrict__ whT, float* __restrict__ wh1, float* __restrict__ wh2) {
    const int tid  = threadIdx.x;
    const int lane = tid & 63;
    const int wid  = tid >> 6;
    const int gw   = blockIdx.x * 4 + wid;
    const int row0 = gw * 8;
    const int b    = row0 >> 11;
    const int rloc = row0 & (NN - 1);

    float acc[8] = {0.f,0.f,0.f,0.f,0.f,0.f,0.f,0.f};
    const float* hrow = h + (size_t)row0 * FIN;

    #pragma unroll 2
    for (int kc = 0; kc < FIN / 4; ++kc) {
        float wv0 = W[(4*kc + 0) * FOUT + lane];
        float wv1 = W[(4*kc + 1) * FOUT + lane];
        float wv2 = W[(4*kc + 2) * FOUT + lane];
        float wv3 = W[(4*kc + 3) * FOUT + lane];
        #pragma unroll
        for (int r = 0; r < 8; ++r) {
            float4 h4 = *(const float4*)(hrow + r * FIN + 4*kc);
            acc[r] = fmaf(h4.x, wv0, acc[r]);
            acc[r] = fmaf(h4.y, wv1, acc[r]);
            acc[r] = fmaf(h4.z, wv2, acc[r]);
            acc[r] = fmaf(h4.w, wv3, acc[r]);
        }
    }

    short8 st;
    #pragma unroll
    for (int r = 0; r < 8; ++r) st[r] = f2bf(acc[r]);
    *(short8*)(whT + ((size_t)b * FOUT + lane) * NN + rloc) = st;

    const float a1 = a[lane];
    const float a2 = a[FOUT + lane];
    #pragma unroll
    for (int r = 0; r < 8; ++r) {
        const int row = row0 + r;
        float v1 = acc[r] * a1;
        float v2 = acc[r] * a2;
        #pragma unroll
        for (int m = 32; m >= 1; m >>= 1) {
            v1 += __shfl_xor(v1, m, 64);
            v2 += __shfl_xor(v2, m, 64);
        }
        if (lane == 0) { wh1[row] = v1; wh2[row] = v2; }
    }
}

// ---------------------------------------------------------------------------
// K2: fused masked-softmax + PV via MFMA, layout-self-calibrated (round-3
// mechanics), restructured for ILP: 2 independent k-tiles per iteration +
// explicit 1-deep register prefetch of next iteration's adj/wh2 stream.
// ---------------------------------------------------------------------------
__global__ __launch_bounds__(256) void k2_attn(
        const float* __restrict__ adj, const short* __restrict__ whT,
        const float* __restrict__ wh1, const float* __restrict__ wh2,
        float* __restrict__ out) {
    __shared__ float lds_acc[4][16][FOUT];
    __shared__ float lds_l[4][16];

    const int tid  = threadIdx.x;
    const int lane = tid & 63;
    const int w    = tid >> 6;
    const int row0 = blockIdx.x * 16;
    const int b    = row0 >> 11;
    const int iloc = lane & 15;
    const int koff = (lane >> 4) * 8;

    const float* adjrow = adj + (size_t)(row0 + iloc) * NN;
    const float* wh2b   = wh2 + b * NN;
    const short* whTb   = whT + (size_t)b * FOUT * NN;
    const float  wh1v   = wh1[row0 + iloc];

    // --- layout self-calibration (proven round 3) ---
    bf16x8 onesf, idxf;
    #pragma unroll
    for (int e = 0; e < 8; ++e) { onesf[e] = (short)0x3F80; idxf[e] = f2bf((float)iloc); }
    f32x4 rowM = {}, colM = {};
    rowM = __builtin_amdgcn_mfma_f32_16x16x32_bf16(idxf, onesf, rowM, 0, 0, 0);
    colM = __builtin_amdgcn_mfma_f32_16x16x32_bf16(onesf, idxf, colM, 0, 0, 0);
    int rmap[4], cmap[4];
    #pragma unroll
    for (int reg = 0; reg < 4; ++reg) {
        int r = (int)(rowM[reg] * 0.03125f + 0.5f);
        int c = (int)(colM[reg] * 0.03125f + 0.5f);
        rmap[reg] = min(max(r, 0), 15);
        cmap[reg] = min(max(c, 0), 15);
    }

    f32x4 acc[4] = {};
    f32x4 accl = {};

    // wave w owns tiles {k*8+w, k*8+w+4}, k=0..7; tile t covers j in [t*32, t*32+32)
    const int base = w * 32 + koff;        // jA(k) = base + k*256, jB = jA + 128

    // prologue: load iteration 0's adj + wh2
    float4 aA0 = *(const float4*)(adjrow + base);
    float4 aA1 = *(const float4*)(adjrow + base + 4);
    float4 aB0 = *(const float4*)(adjrow + base + 128);
    float4 aB1 = *(const float4*)(adjrow + base + 132);
    float4 wA0 = *(const float4*)(wh2b + base);
    float4 wA1 = *(const float4*)(wh2b + base + 4);
    float4 wB0 = *(const float4*)(wh2b + base + 128);
    float4 wB1 = *(const float4*)(wh2b + base + 132);

    #pragma unroll
    for (int k = 0; k < 8; ++k) {
        const int jA = base + k * 256;
        const int jB = jA + 128;

        // issue B-fragment loads for current tiles (L2) — latency hides under exp
        bf16x8 bfA[4], bfB[4];
        #pragma unroll
        for (int ft = 0; ft < 4; ++ft) {
            const short* rp = whTb + (size_t)(ft * 16 + iloc) * NN;
            bfA[ft] = *(const bf16x8*)(rp + jA);
            bfB[ft] = *(const bf16x8*)(rp + jB);
        }

        // prefetch next iteration's adj/wh2 (HBM stream) before any compute
        float4 naA0 = aA0, naA1 = aA1, naB0 = aB0, naB1 = aB1;
        float4 nwA0 = wA0, nwA1 = wA1, nwB0 = wB0, nwB1 = wB1;
        if (k < 7) {
            const float* qA = adjrow + jA + 256;
            const float* qW = wh2b + jA + 256;
            naA0 = *(const float4*)(qA);
            naA1 = *(const float4*)(qA + 4);
            naB0 = *(const float4*)(qA + 128);
            naB1 = *(const float4*)(qA + 132);
            nwA0 = *(const float4*)(qW);
            nwA1 = *(const float4*)(qW + 4);
            nwB0 = *(const float4*)(qW + 128);
            nwB1 = *(const float4*)(qW + 132);
        }

        // score+exp for both tiles — operands already in registers, no mem wait
        bf16x8 afA = score8(wh1v, wA0, wA1, aA0, aA1);
        bf16x8 afB = score8(wh1v, wB0, wB1, aB0, aB1);

        accl = __builtin_amdgcn_mfma_f32_16x16x32_bf16(afA, onesf, accl, 0, 0, 0);
        #pragma unroll
        for (int ft = 0; ft < 4; ++ft)
            acc[ft] = __builtin_amdgcn_mfma_f32_16x16x32_bf16(afA, bfA[ft], acc[ft], 0, 0, 0);
        accl = __builtin_amdgcn_mfma_f32_16x16x32_bf16(afB, onesf, accl, 0, 0, 0);
        #pragma unroll
        for (int ft = 0; ft < 4; ++ft)
            acc[ft] = __builtin_amdgcn_mfma_f32_16x16x32_bf16(afB, bfB[ft], acc[ft], 0, 0, 0);

        // rotate prefetch buffers
        aA0 = naA0; aA1 = naA1; aB0 = naB0; aB1 = naB1;
        wA0 = nwA0; wA1 = nwA1; wB0 = nwB0; wB1 = nwB1;
    }

    // stash partials in LDS using the MEASURED layout maps
    #pragma unroll
    for (int ft = 0; ft < 4; ++ft)
        #pragma unroll
        for (int reg = 0; reg < 4; ++reg)
            lds_acc[w][rmap[reg]][ft * 16 + cmap[reg]] = acc[ft][reg];
    #pragma unroll
    for (int reg = 0; reg < 4; ++reg)
        if (cmap[reg] == 0) lds_l[w][rmap[reg]] = accl[reg];
    __syncthreads();

    // combine across waves + normalize + elu
    const int f  = tid & 63;
    const int r0 = tid >> 6;
    #pragma unroll
    for (int rr = 0; rr < 4; ++rr) {
        const int r = r0 * 4 + rr;
        float s = lds_acc[0][r][f] + lds_acc[1][r][f] + lds_acc[2][r][f] + lds_acc[3][r][f];
        float l = lds_l[0][r] + lds_l[1][r] + lds_l[2][r] + lds_l[3][r];
        float v = s / l;
        out[(size_t)(row0 + r) * FOUT + f] = (v > 0.f) ? v : (__expf(v) - 1.f);
    }
}

// ---------------------------------------------------------------------------
extern "C" void kernel_launch(void* const* d_in, const int* in_sizes, int n_in,
                              void* d_out, int out_size, void* d_ws, size_t ws_size,
                              hipStream_t stream) {
    const float* h   = (const float*)d_in[0];   // [8,2048,128]
    const float* adj = (const float*)d_in[1];   // [8,2048,2048]
    const float* W   = (const float*)d_in[2];   // [128,64]
    const float* a   = (const float*)d_in[3];   // [128,1]
    float* out = (float*)d_out;                 // [8,2048,64]

    short* whT = (short*)d_ws;                             // [8][64][2048] bf16 = 2 MB
    float* wh1 = (float*)(whT + (size_t)BATCH * FOUT * NN);// 16384 f32
    float* wh2 = wh1 + ROWS_TOTAL;                         // 16384 f32

    k1_proj<<<ROWS_TOTAL / 32, 256, 0, stream>>>(h, W, a, whT, wh1, wh2);
    k2_attn<<<ROWS_TOTAL / 16, 256, 0, stream>>>(adj, whT, wh1, wh2, out);
}